// Round 14
// baseline (417.735 us; speedup 1.0000x reference)
//
#include <hip/hip_runtime.h>

#define LL 32
#define HH 64

// Broadcast lane n's value of v to all lanes via v_readlane -> SGPR.
__device__ __forceinline__ float bcast_lane(float v, int n) {
  return __builtin_bit_cast(float, __builtin_amdgcn_readlane(__builtin_bit_cast(int, v), n));
}

template <int CTRL>
__device__ __forceinline__ float dpp_add_step(float x) {
  int y = __builtin_amdgcn_update_dpp(0, __builtin_bit_cast(int, x), CTRL, 0xf, 0xf, true);
  return x + __builtin_bit_cast(float, y);
}

// 64-lane sum -> uniform value (via readlane 63).
__device__ __forceinline__ float wave_sum64(float x) {
  x = dpp_add_step<0x111>(x);  // row_shr:1
  x = dpp_add_step<0x112>(x);  // row_shr:2
  x = dpp_add_step<0x114>(x);  // row_shr:4
  x = dpp_add_step<0x118>(x);  // row_shr:8
  x = dpp_add_step<0x142>(x);  // row_bcast15
  x = dpp_add_step<0x143>(x);  // row_bcast31
  return __builtin_bit_cast(float, __builtin_amdgcn_readlane(__builtin_bit_cast(int, x), 63));
}

#define DECL_W(n) float w_##n = Wc[n * HH + lane];

// Stage one broadcast: readlane n of hv into an SGPR-resident local.
#define RL(n) const float s##n = bcast_lane(hv, n);

// Input-only SGPR pin: forces the 32 staged broadcasts to materialize HERE,
// before any consuming FMA — every readlane's SGPR consumer is then >=32
// instructions downstream, hiding the VALU->SGPR->VALU wait states that made
// R6's per-element interleave stall (~5 cyc x64/step).
#define PIN_S(...) asm volatile("" ::__VA_ARGS__);
#define S32_A                                                                  \
  "s"(s0), "s"(s1), "s"(s2), "s"(s3), "s"(s4), "s"(s5), "s"(s6), "s"(s7),      \
      "s"(s8), "s"(s9), "s"(s10), "s"(s11), "s"(s12), "s"(s13), "s"(s14),      \
      "s"(s15), "s"(s16), "s"(s17), "s"(s18), "s"(s19), "s"(s20), "s"(s21),    \
      "s"(s22), "s"(s23), "s"(s24), "s"(s25), "s"(s26), "s"(s27), "s"(s28),    \
      "s"(s29), "s"(s30), "s"(s31)
#define S32_B                                                                  \
  "s"(s32), "s"(s33), "s"(s34), "s"(s35), "s"(s36), "s"(s37), "s"(s38),        \
      "s"(s39), "s"(s40), "s"(s41), "s"(s42), "s"(s43), "s"(s44), "s"(s45),    \
      "s"(s46), "s"(s47), "s"(s48), "s"(s49), "s"(s50), "s"(s51), "s"(s52),    \
      "s"(s53), "s"(s54), "s"(s55), "s"(s56), "s"(s57), "s"(s58), "s"(s59),    \
      "s"(s60), "s"(s61), "s"(s62), "s"(s63)

// FMA consumption (same i-ascending order / 4-chain assignment as all prior
// rounds -> bit-identical results). v_fmac_f32 dst, s, v — 1 SGPR operand, legal.
#define MVS4(i0, i1, i2, i3)          \
  a0 = fmaf(s##i0, w_##i0, a0);       \
  a1 = fmaf(s##i1, w_##i1, a1);       \
  a2 = fmaf(s##i2, w_##i2, a2);       \
  a3 = fmaf(s##i3, w_##i3, a3);

#define W_OPS_RW                                                               \
  "+v"(w_0), "+v"(w_1), "+v"(w_2), "+v"(w_3), "+v"(w_4), "+v"(w_5),           \
      "+v"(w_6), "+v"(w_7), "+v"(w_8), "+v"(w_9), "+v"(w_10), "+v"(w_11),     \
      "+v"(w_12), "+v"(w_13), "+v"(w_14), "+v"(w_15), "+v"(w_16),             \
      "+v"(w_17), "+v"(w_18), "+v"(w_19), "+v"(w_20), "+v"(w_21),             \
      "+v"(w_22), "+v"(w_23), "+v"(w_24), "+v"(w_25), "+v"(w_26),             \
      "+v"(w_27), "+v"(w_28), "+v"(w_29), "+v"(w_30), "+v"(w_31),             \
      "+v"(w_32), "+v"(w_33), "+v"(w_34), "+v"(w_35), "+v"(w_36),             \
      "+v"(w_37), "+v"(w_38), "+v"(w_39), "+v"(w_40), "+v"(w_41),             \
      "+v"(w_42), "+v"(w_43), "+v"(w_44), "+v"(w_45), "+v"(w_46),             \
      "+v"(w_47), "+v"(w_48), "+v"(w_49), "+v"(w_50), "+v"(w_51),             \
      "+v"(w_52), "+v"(w_53), "+v"(w_54), "+v"(w_55), "+v"(w_56),             \
      "+v"(w_57), "+v"(w_58), "+v"(w_59), "+v"(w_60), "+v"(w_61),             \
      "+v"(w_62), "+v"(w_63), "+v"(win0), "+v"(win1), "+v"(bcj), "+v"(dwout)

#define W_OPS_USE                                                              \
  "v"(w_0), "v"(w_1), "v"(w_2), "v"(w_3), "v"(w_4), "v"(w_5), "v"(w_6),       \
      "v"(w_7), "v"(w_8), "v"(w_9), "v"(w_10), "v"(w_11), "v"(w_12),          \
      "v"(w_13), "v"(w_14), "v"(w_15), "v"(w_16), "v"(w_17), "v"(w_18),       \
      "v"(w_19), "v"(w_20), "v"(w_21), "v"(w_22), "v"(w_23), "v"(w_24),       \
      "v"(w_25), "v"(w_26), "v"(w_27), "v"(w_28), "v"(w_29), "v"(w_30),       \
      "v"(w_31), "v"(w_32), "v"(w_33), "v"(w_34), "v"(w_35), "v"(w_36),       \
      "v"(w_37), "v"(w_38), "v"(w_39), "v"(w_40), "v"(w_41), "v"(w_42),       \
      "v"(w_43), "v"(w_44), "v"(w_45), "v"(w_46), "v"(w_47), "v"(w_48),       \
      "v"(w_49), "v"(w_50), "v"(w_51), "v"(w_52), "v"(w_53), "v"(w_54),       \
      "v"(w_55), "v"(w_56), "v"(w_57), "v"(w_58), "v"(w_59), "v"(w_60),       \
      "v"(w_61), "v"(w_62), "v"(w_63), "v"(win0), "v"(win1), "v"(bcj),        \
      "v"(dwout)

// Weight residency scheme proven in R13 (VGPR 84, no spills): def pin at top +
// per-row def + per-step use-only.
#define PIN_ALL_W_DEF asm volatile("" : W_OPS_RW);
#define PIN_ALL_W_USE asm volatile("" ::W_OPS_USE);

// One wave per sample, 1024 blocks = 1 wave/SIMD on all 1024 SIMDs.
// Matvec broadcast via bulk-staged v_readlane -> SGPR (NO LDS): R8-R13's
// plateau (~860 cyc/step) was the CU-level LDS pipe saturated by 4 waves x
// 16 ds_read_b128/step (~12 cyc each, m134). VALU is per-SIMD -> no
// cross-wave contention on the readlane path. LDS now carries only the
// vertical-carry b32 read+write per step.
__global__ __launch_bounds__(64, 1) void rnn2d_kernel(
    const int* __restrict__ x, const float* __restrict__ Win,
    const float* __restrict__ Wc, const float* __restrict__ bc,
    const float* __restrict__ Wout, const float* __restrict__ bout,
    float* __restrict__ out) {
  const int lane = threadIdx.x;
  const int b = blockIdx.x;
  __shared__ float vrow[LL * HH];  // vertical carry [column][hidden]

  DECL_W(0)  DECL_W(1)  DECL_W(2)  DECL_W(3)  DECL_W(4)  DECL_W(5)  DECL_W(6)  DECL_W(7)
  DECL_W(8)  DECL_W(9)  DECL_W(10) DECL_W(11) DECL_W(12) DECL_W(13) DECL_W(14) DECL_W(15)
  DECL_W(16) DECL_W(17) DECL_W(18) DECL_W(19) DECL_W(20) DECL_W(21) DECL_W(22) DECL_W(23)
  DECL_W(24) DECL_W(25) DECL_W(26) DECL_W(27) DECL_W(28) DECL_W(29) DECL_W(30) DECL_W(31)
  DECL_W(32) DECL_W(33) DECL_W(34) DECL_W(35) DECL_W(36) DECL_W(37) DECL_W(38) DECL_W(39)
  DECL_W(40) DECL_W(41) DECL_W(42) DECL_W(43) DECL_W(44) DECL_W(45) DECL_W(46) DECL_W(47)
  DECL_W(48) DECL_W(49) DECL_W(50) DECL_W(51) DECL_W(52) DECL_W(53) DECL_W(54) DECL_W(55)
  DECL_W(56) DECL_W(57) DECL_W(58) DECL_W(59) DECL_W(60) DECL_W(61) DECL_W(62) DECL_W(63)

  float win0 = Win[lane];
  float win1 = Win[HH + lane];
  float bcj = bc[lane];
  float dwout = Wout[lane * 2 + 1] - Wout[lane * 2 + 0];
  const float dbout = bout[1] - bout[0];
  PIN_ALL_W_DEF  // asm-defined: remat-as-load impossible (R10 lesson)

  // Row 0 sees zero vertical hidden carry.
#pragma unroll
  for (int c0 = 0; c0 < LL; ++c0) vrow[c0 * HH + lane] = 0.f;

  const int* xb = x + b * (LL * LL);
  unsigned prevmask = 0u;                // previous row's spins (bit c = spin at col c)
  int spv = (lane < LL) ? xb[lane] : 0;  // prefetched row-0 spins
  float total_vec = 0.f;                 // per-lane partial of sum(logp)
  float dzbuf = 0.f;                     // lane k holds step-k signed logit gap
  float hv = 0.f;                        // (hcur + vj) carried in registers; at a
                                         // row boundary hv = hnew (same column
                                         // re-entry, zero horizontal carry)

#pragma unroll 1
  for (int r = 0; r < LL; ++r) {
    const unsigned curmask =
        (unsigned)(__ballot(lane < LL && spv) & 0xffffffffull);
    if (r < LL - 1) spv = (lane < LL) ? xb[(r + 1) * LL + lane] : 0;

    PIN_ALL_W_DEF  // per-row def point (32 executions total, cheap)

    const int odd = r & 1;
    const int d = odd ? -1 : 1;       // boustrophedon direction
    int c = odd ? (LL - 1) : 0;       // spatial column of scan step 0

#pragma unroll 2
    for (int k = 0; k < LL; ++k) {
      PIN_ALL_W_USE  // zero-instruction liveness pressure

      // Prefetch next step's vertical carry (lane-strided b32; that column is
      // not yet overwritten this row). Only LDS read in the step.
      const int cn = (c + d) & (LL - 1);
      const float vjn = (k < LL - 1) ? vrow[cn * HH + lane] : 0.f;

      // Chunk A: broadcasts 0..31 staged to SGPRs, then 32 FMAs.
      float a0 = 0.f, a1 = 0.f, a2 = 0.f, a3 = 0.f;
      RL(0)  RL(1)  RL(2)  RL(3)  RL(4)  RL(5)  RL(6)  RL(7)
      RL(8)  RL(9)  RL(10) RL(11) RL(12) RL(13) RL(14) RL(15)
      RL(16) RL(17) RL(18) RL(19) RL(20) RL(21) RL(22) RL(23)
      RL(24) RL(25) RL(26) RL(27) RL(28) RL(29) RL(30) RL(31)
      PIN_S(S32_A)
      MVS4(0, 1, 2, 3)     MVS4(4, 5, 6, 7)     MVS4(8, 9, 10, 11)
      MVS4(12, 13, 14, 15) MVS4(16, 17, 18, 19) MVS4(20, 21, 22, 23)
      MVS4(24, 25, 26, 27) MVS4(28, 29, 30, 31)

      // Chunk B: broadcasts 32..63 (SGPR peak stays ~70 < 102 limit).
      RL(32) RL(33) RL(34) RL(35) RL(36) RL(37) RL(38) RL(39)
      RL(40) RL(41) RL(42) RL(43) RL(44) RL(45) RL(46) RL(47)
      RL(48) RL(49) RL(50) RL(51) RL(52) RL(53) RL(54) RL(55)
      RL(56) RL(57) RL(58) RL(59) RL(60) RL(61) RL(62) RL(63)
      PIN_S(S32_B)
      MVS4(32, 33, 34, 35) MVS4(36, 37, 38, 39) MVS4(40, 41, 42, 43)
      MVS4(44, 45, 46, 47) MVS4(48, 49, 50, 51) MVS4(52, 53, 54, 55)
      MVS4(56, 57, 58, 59) MVS4(60, 61, 62, 63)

      // newR @ Win: one-hot selects (spins are wave-uniform bits of the masks).
      float winc = 0.f;
      if (k > 0) {
        const unsigned sh = (curmask >> ((c - d) & 31)) & 1u;
        winc += sh ? win1 : win0;
      }
      if (r > 0) {
        const unsigned sv = (prevmask >> c) & 1u;
        winc += sv ? win1 : win0;
      }

      const float pre = ((a0 + a1) + (a2 + a3)) + bcj + winc;
      const float hnew = pre > 0.f ? pre : (__expf(pre) - 1.f);  // elu

      vrow[c * HH + lane] = hnew;  // vertical carry for next row
      hv = hnew + vjn;             // next step's broadcast source (register)

      // Deferred logp: stash signed logit gap t_k in lane k; softplus once/row.
      const float dzv = wave_sum64(hnew * dwout) + dbout;  // z1 - z0, uniform
      const unsigned spin = (curmask >> c) & 1u;
      const float tv = __builtin_bit_cast(
          float, __builtin_bit_cast(unsigned, dzv) ^ (spin << 31));
      dzbuf = (lane == k) ? tv : dzbuf;

      c = cn;
    }
    prevmask = curmask;

    // Row epilogue: softplus for all 32 steps at once (lanes 0..31 hold t_k).
    const float tt = dzbuf;
    float lpv = -(fmaxf(tt, 0.f) + __logf(1.f + __expf(-fabsf(tt))));
    lpv = (lpv == lpv) ? lpv : -35.0f;  // nan_to_num(nan=-35)
    total_vec += (lane < LL) ? lpv : 0.f;
  }

  const float grand = wave_sum64(total_vec);
  if (lane == 0) out[b] = 0.5f * grand;  // LOGP_FACTOR * sum
}

extern "C" void kernel_launch(void* const* d_in, const int* in_sizes, int n_in,
                              void* d_out, int out_size, void* d_ws, size_t ws_size,
                              hipStream_t stream) {
  const int* x = (const int*)d_in[0];
  const float* Win = (const float*)d_in[1];
  const float* Wc = (const float*)d_in[2];
  const float* bc = (const float*)d_in[3];
  const float* Wout = (const float*)d_in[4];
  const float* bout = (const float*)d_in[5];
  float* out = (float*)d_out;
  rnn2d_kernel<<<dim3(out_size), dim3(64), 0, stream>>>(x, Win, Wc, bc, Wout, bout, out);
}